// Round 11
// baseline (330.225 us; speedup 1.0000x reference)
//
#include <hip/hip_runtime.h>
#include <hip/hip_bf16.h>

// GIN: 2 x (padded-CSR gather-sum + MLP(64->64->64) + BatchNorm + ReLU) + mean pool
// N=50000 nodes, E=800000 edges, H=64, G=16 graphs. fp32 in/out.
// R25 = R23 (best known, 273.4us) + pool finalize folded into norm_kernel via
// last-block-done atomic (prep zeroes `done`; the norm block that sees
// fetch_add == grid-1 reads psums with agent-scope atomic loads and writes
// the means). 8 -> 7 dispatches. R24's column-halved gather reverted: halves
// interleave (no temporal separation) and doubled per-row overhead (+16us).
// 7 dispatches: prep, scatter, agg, mlp, aggn, mlp, norm(+finalize).

constexpr int NN = 50000;
constexpr int NE = 800000;
constexpr int HD = 64;
constexpr int NG = 16;
constexpr float BN_EPS = 1e-5f;
constexpr int ROWCAP = 64;   // max degree capacity; P(deg>64)~1e-20 at E/N=16
constexpr int NPART = 8;     // XCD partitions
constexpr int PSZ = 6250;    // rows per partition
constexpr int PBLK = (PSZ + 3) / 4;    // 1563 agg blocks per partition
constexpr int NORM_GRID = (NN * HD / 4 + 255) / 256;  // 3125

// ---------------------------------------------------------------------------
// Prep: fp32 -> bf16 table conversion; zero cnt[], stats0/1, psums, done.
// ---------------------------------------------------------------------------
__global__ __launch_bounds__(256)
void prep_kernel(const float* __restrict__ x, __hip_bfloat16* __restrict__ xb,
                 int* __restrict__ cnt, float* __restrict__ stats0,
                 float* __restrict__ stats1, float* __restrict__ psums,
                 unsigned int* __restrict__ done) {
    int i4 = blockIdx.x * 256 + threadIdx.x;
    if (i4 < NN) cnt[i4] = 0;
    if (blockIdx.x == 0) {
        if (threadIdx.x < 128) stats0[threadIdx.x] = 0.f;
        else stats1[threadIdx.x - 128] = 0.f;
    } else if (blockIdx.x == 1) {
        *(float4*)(psums + threadIdx.x * 4) = make_float4(0.f, 0.f, 0.f, 0.f);
    } else if (blockIdx.x == 2 && threadIdx.x == 0) {
        *done = 0u;
    }
    if (i4 >= NN * HD / 4) return;
    float4 v = *(const float4*)(x + (size_t)i4 * 4);
    union { ushort4 u; __hip_bfloat16 b[4]; } p;
    p.b[0] = __float2bfloat16(v.x);
    p.b[1] = __float2bfloat16(v.y);
    p.b[2] = __float2bfloat16(v.z);
    p.b[3] = __float2bfloat16(v.w);
    *(ushort4*)((unsigned short*)xb + (size_t)i4 * 4) = p.u;
}

// ---------------------------------------------------------------------------
// XCD-partitioned scatter into degree-padded ushort CSR (R16, unchanged).
// Block b: partition b&7 (round-robin blockIdx->XCD), edge chunk b>>3.
// ---------------------------------------------------------------------------
__global__ __launch_bounds__(256)
void scatter_kernel(const int* __restrict__ ei, int* __restrict__ cnt,
                    unsigned short* __restrict__ csr) {
    int p = blockIdx.x & 7;
    int chunk = blockIdx.x >> 3;
    int e4 = (chunk * 256 + threadIdx.x) * 4;
    if (e4 >= NE) return;
    int4 s = *(const int4*)(ei + e4);
    int4 d = *(const int4*)(ei + NE + e4);
    int lo = p * PSZ, hi = lo + PSZ;
    int slot;
    if (d.x >= lo && d.x < hi) {
        slot = atomicAdd(&cnt[d.x], 1);
        if (slot < ROWCAP) csr[(d.x << 6) + slot] = (unsigned short)s.x;
    }
    if (d.y >= lo && d.y < hi) {
        slot = atomicAdd(&cnt[d.y], 1);
        if (slot < ROWCAP) csr[(d.y << 6) + slot] = (unsigned short)s.y;
    }
    if (d.z >= lo && d.z < hi) {
        slot = atomicAdd(&cnt[d.z], 1);
        if (slot < ROWCAP) csr[(d.z << 6) + slot] = (unsigned short)s.z;
    }
    if (d.w >= lo && d.w < hi) {
        slot = atomicAdd(&cnt[d.w], 1);
        if (slot < ROWCAP) csr[(d.w << 6) + slot] = (unsigned short)s.w;
    }
}

// ---------------------------------------------------------------------------
// Aggregation, 4-rows-per-instruction (R23, unchanged). One wave per dst row
// (R16 partition mapping). lane l: group g=l>>4 handles neighbors j+g; slot
// s=l&15 covers columns 4s..4s+3 (uint2). shfl_xor(16,32) butterfly merges.
// MODE 0: raw. MODE 1: apply prev-layer BN+ReLU per gathered value.
// ---------------------------------------------------------------------------
template <int MODE>
__global__ __launch_bounds__(256)
void agg_kernel(const float* __restrict__ xin, const __hip_bfloat16* __restrict__ xg,
                const int* __restrict__ cnt, const unsigned short* __restrict__ csr,
                const float* __restrict__ stats_prev, const float* __restrict__ gp,
                const float* __restrict__ bep, float* __restrict__ h) {
    int lr = ((blockIdx.x >> 3) << 2) + (threadIdx.x >> 6);
    if (lr >= PSZ) return;
    int row = (blockIdx.x & 7) * PSZ + lr;
    int lane = threadIdx.x & 63;
    int s4 = (lane & 15) * 4;   // column base for this lane
    int g = lane >> 4;          // neighbor group 0..3

    float4 sc4 = make_float4(1.f, 1.f, 1.f, 1.f);
    float4 off4 = make_float4(0.f, 0.f, 0.f, 0.f);
    if (MODE == 1) {
        const float inv = 1.f / (float)NN;
        float4 sm = *(const float4*)(stats_prev + s4);
        float4 sq = *(const float4*)(stats_prev + 64 + s4);
        float4 gg = *(const float4*)(gp + s4);
        float4 bb = *(const float4*)(bep + s4);
        float mu, var;
        mu = sm.x * inv; var = sq.x * inv - mu * mu;
        sc4.x = gg.x * rsqrtf(var + BN_EPS); off4.x = bb.x - mu * sc4.x;
        mu = sm.y * inv; var = sq.y * inv - mu * mu;
        sc4.y = gg.y * rsqrtf(var + BN_EPS); off4.y = bb.y - mu * sc4.y;
        mu = sm.z * inv; var = sq.z * inv - mu * mu;
        sc4.z = gg.z * rsqrtf(var + BN_EPS); off4.z = bb.z - mu * sc4.z;
        mu = sm.w * inv; var = sq.w * inv - mu * mu;
        sc4.w = gg.w * rsqrtf(var + BN_EPS); off4.w = bb.w - mu * sc4.w;
    }

    int m = min(cnt[row], ROWCAP);
    int ids = (int)csr[((size_t)row << 6) + lane];
    const unsigned short* xgp = (const unsigned short*)xg;

    float4 accA = make_float4(0.f, 0.f, 0.f, 0.f);
    float4 accB = make_float4(0.f, 0.f, 0.f, 0.f);
    if (g == 0) {  // self term added by group 0 only
        float4 sv = *(const float4*)(xin + (size_t)row * HD + s4);
        if (MODE == 1) {
            accA.x = fmaxf(fmaf(sv.x, sc4.x, off4.x), 0.f);
            accA.y = fmaxf(fmaf(sv.y, sc4.y, off4.y), 0.f);
            accA.z = fmaxf(fmaf(sv.z, sc4.z, off4.z), 0.f);
            accA.w = fmaxf(fmaf(sv.w, sc4.w, off4.w), 0.f);
        } else {
            accA = sv;
        }
    }

#define ACC_U2(ACC, U)                                                        \
    {                                                                         \
        float v0 = __uint_as_float((U).x << 16);                              \
        float v1 = __uint_as_float((U).x & 0xffff0000u);                      \
        float v2 = __uint_as_float((U).y << 16);                              \
        float v3 = __uint_as_float((U).y & 0xffff0000u);                      \
        if (MODE == 1) {                                                      \
            ACC.x += fmaxf(fmaf(v0, sc4.x, off4.x), 0.f);                     \
            ACC.y += fmaxf(fmaf(v1, sc4.y, off4.y), 0.f);                     \
            ACC.z += fmaxf(fmaf(v2, sc4.z, off4.z), 0.f);                     \
            ACC.w += fmaxf(fmaf(v3, sc4.w, off4.w), 0.f);                     \
        } else {                                                              \
            ACC.x += v0; ACC.y += v1; ACC.z += v2; ACC.w += v3;               \
        }                                                                     \
    }

    int j = 0;
    for (; j + 8 <= m; j += 8) {  // 8 neighbors per iter: 2 loads/lane
        int nb0 = __shfl(ids, j + g);
        int nb1 = __shfl(ids, j + 4 + g);
        uint2 u0 = *(const uint2*)(xgp + ((size_t)nb0 << 6) + s4);
        uint2 u1 = *(const uint2*)(xgp + ((size_t)nb1 << 6) + s4);
        ACC_U2(accA, u0);
        ACC_U2(accB, u1);
    }
    for (; j < m; j += 4) {  // tail: up to 4 neighbors, predicated by group
        int nb = __shfl(ids, j + g);  // j wave-uniform; shfl unconditional
        if (j + g < m) {
            uint2 u = *(const uint2*)(xgp + ((size_t)nb << 6) + s4);
            ACC_U2(accA, u);
        }
    }
#undef ACC_U2

    float4 acc = make_float4(accA.x + accB.x, accA.y + accB.y,
                             accA.z + accB.z, accA.w + accB.w);
    // butterfly across the 4 groups (lanes xor 16, 32)
    acc.x += __shfl_xor(acc.x, 16);
    acc.y += __shfl_xor(acc.y, 16);
    acc.z += __shfl_xor(acc.z, 16);
    acc.w += __shfl_xor(acc.w, 16);
    acc.x += __shfl_xor(acc.x, 32);
    acc.y += __shfl_xor(acc.y, 32);
    acc.z += __shfl_xor(acc.z, 32);
    acc.w += __shfl_xor(acc.w, 32);

    if (g == 0)
        *(float4*)(h + (size_t)row * HD + s4) = acc;
}

// ---------------------------------------------------------------------------
// Fused MLP + BN-stats epilogue (R16, unchanged). Optional bf16 dual-write.
// ---------------------------------------------------------------------------
__global__ __launch_bounds__(256)
void mlp_kernel(const float* __restrict__ hin, float* __restrict__ hout,
                const float* __restrict__ W1, const float* __restrict__ b1,
                const float* __restrict__ W2, const float* __restrict__ b2,
                float* __restrict__ stats, __hip_bfloat16* __restrict__ xbr) {
    __shared__ float sh[128 * 65];
    __shared__ float sW[64 * 64];
    __shared__ float sb[64];
    __shared__ float red[2][4][64];
    int tid = threadIdx.x;
    int base = blockIdx.x * 128;

    for (int i = tid; i < 4096; i += 256) sW[i] = W1[i];
    if (tid < 64) sb[tid] = b1[tid];
#pragma unroll
    for (int i = 0; i < 8; i++) {
        int i4 = tid + 256 * i;
        int row = i4 >> 4, col = (i4 & 15) * 4;
        int grow = base + row;
        float4 v = (grow < NN) ? *(const float4*)(hin + (size_t)grow * HD + col)
                               : make_float4(0.f, 0.f, 0.f, 0.f);
        float* d = sh + row * 65 + col;
        d[0] = v.x; d[1] = v.y; d[2] = v.z; d[3] = v.w;
    }
    __syncthreads();

    int wv = tid >> 6;
    int lane = tid & 63;

    float acc0[16], acc1[16];
    // ---- GEMM1 ----
#pragma unroll
    for (int j = 0; j < 16; j++) { acc0[j] = sb[wv * 16 + j]; acc1[j] = acc0[j]; }
    for (int k = 0; k < 64; k++) {
        float a0 = sh[lane * 65 + k];
        float a1 = sh[(64 + lane) * 65 + k];
        const float4* wr = (const float4*)(sW + k * 64 + wv * 16);
#pragma unroll
        for (int q = 0; q < 4; q++) {
            float4 w = wr[q];
            acc0[4 * q + 0] = fmaf(a0, w.x, acc0[4 * q + 0]);
            acc0[4 * q + 1] = fmaf(a0, w.y, acc0[4 * q + 1]);
            acc0[4 * q + 2] = fmaf(a0, w.z, acc0[4 * q + 2]);
            acc0[4 * q + 3] = fmaf(a0, w.w, acc0[4 * q + 3]);
            acc1[4 * q + 0] = fmaf(a1, w.x, acc1[4 * q + 0]);
            acc1[4 * q + 1] = fmaf(a1, w.y, acc1[4 * q + 1]);
            acc1[4 * q + 2] = fmaf(a1, w.z, acc1[4 * q + 2]);
            acc1[4 * q + 3] = fmaf(a1, w.w, acc1[4 * q + 3]);
        }
    }
    __syncthreads();

    // t = ReLU(acc) overwrites sh; restage W2/b2
#pragma unroll
    for (int j = 0; j < 16; j++) {
        sh[lane * 65 + wv * 16 + j] = fmaxf(acc0[j], 0.f);
        sh[(64 + lane) * 65 + wv * 16 + j] = fmaxf(acc1[j], 0.f);
    }
    for (int i = tid; i < 4096; i += 256) sW[i] = W2[i];
    if (tid < 64) sb[tid] = b2[tid];
    __syncthreads();

    // ---- GEMM2 ----
#pragma unroll
    for (int j = 0; j < 16; j++) { acc0[j] = sb[wv * 16 + j]; acc1[j] = acc0[j]; }
    for (int k = 0; k < 64; k++) {
        float a0 = sh[lane * 65 + k];
        float a1 = sh[(64 + lane) * 65 + k];
        const float4* wr = (const float4*)(sW + k * 64 + wv * 16);
#pragma unroll
        for (int q = 0; q < 4; q++) {
            float4 w = wr[q];
            acc0[4 * q + 0] = fmaf(a0, w.x, acc0[4 * q + 0]);
            acc0[4 * q + 1] = fmaf(a0, w.y, acc0[4 * q + 1]);
            acc0[4 * q + 2] = fmaf(a0, w.z, acc0[4 * q + 2]);
            acc0[4 * q + 3] = fmaf(a0, w.w, acc0[4 * q + 3]);
            acc1[4 * q + 0] = fmaf(a1, w.x, acc1[4 * q + 0]);
            acc1[4 * q + 1] = fmaf(a1, w.y, acc1[4 * q + 1]);
            acc1[4 * q + 2] = fmaf(a1, w.z, acc1[4 * q + 2]);
            acc1[4 * q + 3] = fmaf(a1, w.w, acc1[4 * q + 3]);
        }
    }
    __syncthreads();
#pragma unroll
    for (int j = 0; j < 16; j++) {
        sh[lane * 65 + wv * 16 + j] = acc0[j];
        sh[(64 + lane) * 65 + wv * 16 + j] = acc1[j];
    }
    __syncthreads();

    // coalesced stores: fp32 always; bf16 raw table if requested
#pragma unroll
    for (int i = 0; i < 8; i++) {
        int i4 = tid + 256 * i;
        int row = i4 >> 4, col = (i4 & 15) * 4;
        int grow = base + row;
        if (grow < NN) {
            const float* s = sh + row * 65 + col;
            float4 v = make_float4(s[0], s[1], s[2], s[3]);
            *(float4*)(hout + (size_t)grow * HD + col) = v;
            if (xbr) {
                union { ushort4 u; __hip_bfloat16 b[4]; } p;
                p.b[0] = __float2bfloat16(v.x);
                p.b[1] = __float2bfloat16(v.y);
                p.b[2] = __float2bfloat16(v.z);
                p.b[3] = __float2bfloat16(v.w);
                *(ushort4*)((unsigned short*)xbr + (size_t)grow * HD + col) = p.u;
            }
        }
    }

    // ---- fused BN-stats partials ----
    {
        int col = tid & 63;
        int r0 = (tid >> 6) * 32;
        float s = 0.f, ss = 0.f;
#pragma unroll
        for (int r = 0; r < 32; r++) {
            float v = (base + r0 + r < NN) ? sh[(r0 + r) * 65 + col] : 0.f;
            s += v;
            ss += v * v;
        }
        red[0][tid >> 6][col] = s;
        red[1][tid >> 6][col] = ss;
        __syncthreads();
        if (tid < 64) {
            float S = red[0][0][col] + red[0][1][col] + red[0][2][col] + red[0][3][col];
            atomicAdd(stats + col, S);
        } else if (tid < 128) {
            float SS = red[1][0][col] + red[1][1][col] + red[1][2][col] + red[1][3][col];
            atomicAdd(stats + 64 + col, SS);
        }
    }
}

// ---------------------------------------------------------------------------
// Final BatchNorm + affine + ReLU with fused mean-pool partials (R16) and
// last-block pool finalize (R25): the block whose done-counter fetch_add
// returns NORM_GRID-1 reads psums via agent-scope atomic loads and writes
// the per-graph means. No extra dispatch.
// ---------------------------------------------------------------------------
__device__ __forceinline__ int lower_bound_batch(const int* __restrict__ b, int val) {
    int lo = 0, hi = NN;
    while (lo < hi) {
        int mid = (lo + hi) >> 1;
        if (b[mid] < val) lo = mid + 1;
        else hi = mid;
    }
    return lo;
}

__global__ __launch_bounds__(256)
void norm_kernel(float* h, const float* __restrict__ stats,
                 const float* __restrict__ g, const float* __restrict__ be,
                 const int* __restrict__ batch, float* __restrict__ psums,
                 unsigned int* __restrict__ done, float* __restrict__ pool_out) {
    __shared__ float sg[2][64];
    __shared__ unsigned int is_last;
    if (threadIdx.x < 128) sg[threadIdx.x >> 6][threadIdx.x & 63] = 0.f;
    __syncthreads();
    size_t i4 = (size_t)blockIdx.x * 256 + threadIdx.x;
    int row = (int)(i4 >> 4);            // 16 threads (4 cols each) per row
    int base_row = blockIdx.x * 16;
    int g0 = batch[base_row];
    size_t off = i4 * 4;
    int col = (int)(off & 63);
    float4 v = *(const float4*)(h + off);
    float4 sm = *(const float4*)(stats + col);
    float4 sq = *(const float4*)(stats + 64 + col);
    float4 gg = *(const float4*)(g + col);
    float4 bb = *(const float4*)(be + col);
    const float inv = 1.f / (float)NN;
    float4 o;
    {
        float mu = sm.x * inv, var = sq.x * inv - mu * mu;
        float sc = gg.x * rsqrtf(var + BN_EPS);
        o.x = fmaxf((v.x - mu) * sc + bb.x, 0.f);
    }
    {
        float mu = sm.y * inv, var = sq.y * inv - mu * mu;
        float sc = gg.y * rsqrtf(var + BN_EPS);
        o.y = fmaxf((v.y - mu) * sc + bb.y, 0.f);
    }
    {
        float mu = sm.z * inv, var = sq.z * inv - mu * mu;
        float sc = gg.z * rsqrtf(var + BN_EPS);
        o.z = fmaxf((v.z - mu) * sc + bb.z, 0.f);
    }
    {
        float mu = sm.w * inv, var = sq.w * inv - mu * mu;
        float sc = gg.w * rsqrtf(var + BN_EPS);
        o.w = fmaxf((v.w - mu) * sc + bb.w, 0.f);
    }
    *(float4*)(h + off) = o;

    // pool partials
    int dg = batch[row] - g0;
    if (dg <= 1) {
        atomicAdd(&sg[dg][col + 0], o.x);
        atomicAdd(&sg[dg][col + 1], o.y);
        atomicAdd(&sg[dg][col + 2], o.z);
        atomicAdd(&sg[dg][col + 3], o.w);
    } else {  // >2 graphs in one 16-row window (never at ~3125 rows/graph)
        int gid = g0 + dg;
        atomicAdd(&psums[gid * HD + col + 0], o.x);
        atomicAdd(&psums[gid * HD + col + 1], o.y);
        atomicAdd(&psums[gid * HD + col + 2], o.z);
        atomicAdd(&psums[gid * HD + col + 3], o.w);
    }
    __syncthreads();
    if (threadIdx.x < 128) {
        int d = threadIdx.x >> 6;
        int c = threadIdx.x & 63;
        float s = sg[d][c];
        if (g0 + d < NG && s != 0.f) atomicAdd(&psums[(g0 + d) * HD + c], s);
    }
    __syncthreads();  // drain this block's psums atomics before arrival

    // ---- last-block pool finalize ----
    if (threadIdx.x == 0) {
        unsigned int prev = __hip_atomic_fetch_add(done, 1u, __ATOMIC_ACQ_REL,
                                                   __HIP_MEMORY_SCOPE_AGENT);
        is_last = (prev == (unsigned int)(NORM_GRID - 1)) ? 1u : 0u;
    }
    __syncthreads();
    if (is_last) {
        for (int idx = threadIdx.x; idx < NG * HD; idx += 256) {
            int gr = idx >> 6;
            int c = idx & 63;
            int s = lower_bound_batch(batch, gr);
            int e = lower_bound_batch(batch, gr + 1);
            float cntf = (float)(e - s);
            float sum = __hip_atomic_load(&psums[idx], __ATOMIC_RELAXED,
                                          __HIP_MEMORY_SCOPE_AGENT);
            pool_out[idx] = sum / fmaxf(cntf, 1.f);
        }
    }
}

extern "C" void kernel_launch(void* const* d_in, const int* in_sizes, int n_in,
                              void* d_out, int out_size, void* d_ws, size_t ws_size,
                              hipStream_t stream) {
    const float* x = (const float*)d_in[0];
    const int* ei = (const int*)d_in[1];
    const int* batch = (const int*)d_in[2];
    const float* W1_0 = (const float*)d_in[3];
    const float* b1_0 = (const float*)d_in[4];
    const float* W2_0 = (const float*)d_in[5];
    const float* b2_0 = (const float*)d_in[6];
    const float* g_0 = (const float*)d_in[7];
    const float* be_0 = (const float*)d_in[8];
    const float* W1_1 = (const float*)d_in[9];
    const float* b1_1 = (const float*)d_in[10];
    const float* W2_1 = (const float*)d_in[11];
    const float* b2_1 = (const float*)d_in[12];
    const float* g_1 = (const float*)d_in[13];
    const float* be_1 = (const float*)d_in[14];

    float* out = (float*)d_out;  // raw L0 h2 -> raw L1 h2 -> final normalized

    // workspace layout (~26 MB)
    float* buf_h = (float*)d_ws;                       // NN*HD f32 (12.8 MB)
    float* stats0 = buf_h + (size_t)NN * HD;           // 128 f32
    float* stats1 = stats0 + 128;                      // 128 f32
    float* psums = stats1 + 128;                       // 1024 f32
    unsigned int* done = (unsigned int*)(psums + 1024);// 1 u32 (+pad 16)
    int* cnt = (int*)(done + 16);                      // NN int
    unsigned short* csr = (unsigned short*)(cnt + NN); // NN*ROWCAP u16 (6.4 MB)
    __hip_bfloat16* xb = (__hip_bfloat16*)(csr + (size_t)NN * ROWCAP);  // NN*HD bf16

    dim3 b256(256);
    int mlp_grid = (NN + 127) / 128;              // 391
    int sct_grid = ((NE + 1023) / 1024) * NPART;  // 782 chunks x 8 = 6256
    int agg_grid = NPART * PBLK;                  // 8 x 1563 = 12504

    // ---- padded-CSR build (2 dispatches) ----
    prep_kernel<<<NORM_GRID, b256, 0, stream>>>(x, xb, cnt, stats0, stats1,
                                                psums, done);
    scatter_kernel<<<sct_grid, b256, 0, stream>>>(ei, cnt, csr);

    // ---- layer 0 ----
    agg_kernel<0><<<agg_grid, b256, 0, stream>>>(x, xb, cnt, csr,
                                                 nullptr, nullptr, nullptr, buf_h);
    // mlp writes raw-L0 bf16 back into xb: safe under dispatch boundaries
    // (agg has fully consumed xb before mlp starts).
    mlp_kernel<<<mlp_grid, b256, 0, stream>>>(buf_h, out, W1_0, b1_0, W2_0, b2_0,
                                              stats0, xb);

    // ---- layer 1 (agg applies layer-0 BN+ReLU on the fly) ----
    agg_kernel<1><<<agg_grid, b256, 0, stream>>>(out, xb, cnt, csr,
                                                 stats0, g_0, be_0, buf_h);
    mlp_kernel<<<mlp_grid, b256, 0, stream>>>(buf_h, out, W1_1, b1_1, W2_1, b2_1,
                                              stats1, (__hip_bfloat16*)nullptr);

    // ---- final norm + fused pool partials + last-block finalize ----
    norm_kernel<<<NORM_GRID, b256, 0, stream>>>(out, stats1, g_1, be_1, batch,
                                                psums, done,
                                                out + (size_t)NN * HD);
}

// Round 12
// 272.774 us; speedup vs baseline: 1.2106x; 1.2106x over previous
//
#include <hip/hip_runtime.h>
#include <hip/hip_bf16.h>

// GIN: 2 x (padded-CSR gather-sum + MLP(64->64->64) + BatchNorm + ReLU) + mean pool
// N=50000 nodes, E=800000 edges, H=64, G=16 graphs. fp32 in/out.
// R26 = R23 verbatim (session best, 273.4us). Reverts R24 (column-halved
// gather: halves interleave, +16us) and R25 (last-block finalize: 3125
// acq-rel RMWs on one line serialize, +57us). Session law, three-times
// measured (R21 grid.sync 600us/barrier, R22 polled counter 160us/barrier,
// R25 single-line done counter 95us): on MI355X, any grid-completion signal
// through memory costs >> the ~10us hardware dispatch boundary. The split
// pipeline with 8 dispatches IS the optimal synchronization structure here.
// Residual time: 2x ~30us latency-bound random gathers (800K x 128B random
// rows/layer, full occupancy, issue-width-insensitive per R23) + ~60us of
// near-BW-floor streaming/MLP kernels + ~80us boundary tax.
// 8 dispatches: prep, scatter, agg, mlp, aggn, mlp, norm, finalize.

constexpr int NN = 50000;
constexpr int NE = 800000;
constexpr int HD = 64;
constexpr int NG = 16;
constexpr float BN_EPS = 1e-5f;
constexpr int ROWCAP = 64;   // max degree capacity; P(deg>64)~1e-20 at E/N=16
constexpr int NPART = 8;     // XCD partitions
constexpr int PSZ = 6250;    // rows per partition
constexpr int PBLK = (PSZ + 3) / 4;  // 1563 agg blocks per partition

// ---------------------------------------------------------------------------
// Prep: fp32 -> bf16 table conversion; zero cnt[], stats0/1, psums.
// ---------------------------------------------------------------------------
__global__ __launch_bounds__(256)
void prep_kernel(const float* __restrict__ x, __hip_bfloat16* __restrict__ xb,
                 int* __restrict__ cnt, float* __restrict__ stats0,
                 float* __restrict__ stats1, float* __restrict__ psums) {
    int i4 = blockIdx.x * 256 + threadIdx.x;
    if (i4 < NN) cnt[i4] = 0;
    if (blockIdx.x == 0) {
        if (threadIdx.x < 128) stats0[threadIdx.x] = 0.f;
        else stats1[threadIdx.x - 128] = 0.f;
    } else if (blockIdx.x == 1) {
        *(float4*)(psums + threadIdx.x * 4) = make_float4(0.f, 0.f, 0.f, 0.f);
    }
    if (i4 >= NN * HD / 4) return;
    float4 v = *(const float4*)(x + (size_t)i4 * 4);
    union { ushort4 u; __hip_bfloat16 b[4]; } p;
    p.b[0] = __float2bfloat16(v.x);
    p.b[1] = __float2bfloat16(v.y);
    p.b[2] = __float2bfloat16(v.z);
    p.b[3] = __float2bfloat16(v.w);
    *(ushort4*)((unsigned short*)xb + (size_t)i4 * 4) = p.u;
}

// ---------------------------------------------------------------------------
// XCD-partitioned scatter into degree-padded ushort CSR (R16, unchanged).
// Block b: partition b&7 (round-robin blockIdx->XCD), edge chunk b>>3.
// ---------------------------------------------------------------------------
__global__ __launch_bounds__(256)
void scatter_kernel(const int* __restrict__ ei, int* __restrict__ cnt,
                    unsigned short* __restrict__ csr) {
    int p = blockIdx.x & 7;
    int chunk = blockIdx.x >> 3;
    int e4 = (chunk * 256 + threadIdx.x) * 4;
    if (e4 >= NE) return;
    int4 s = *(const int4*)(ei + e4);
    int4 d = *(const int4*)(ei + NE + e4);
    int lo = p * PSZ, hi = lo + PSZ;
    int slot;
    if (d.x >= lo && d.x < hi) {
        slot = atomicAdd(&cnt[d.x], 1);
        if (slot < ROWCAP) csr[(d.x << 6) + slot] = (unsigned short)s.x;
    }
    if (d.y >= lo && d.y < hi) {
        slot = atomicAdd(&cnt[d.y], 1);
        if (slot < ROWCAP) csr[(d.y << 6) + slot] = (unsigned short)s.y;
    }
    if (d.z >= lo && d.z < hi) {
        slot = atomicAdd(&cnt[d.z], 1);
        if (slot < ROWCAP) csr[(d.z << 6) + slot] = (unsigned short)s.z;
    }
    if (d.w >= lo && d.w < hi) {
        slot = atomicAdd(&cnt[d.w], 1);
        if (slot < ROWCAP) csr[(d.w << 6) + slot] = (unsigned short)s.w;
    }
}

// ---------------------------------------------------------------------------
// Aggregation, 4-rows-per-instruction (R23). One wave per dst row (R16
// partition mapping: same XCD that scattered the row's CSR lines reads them
// back). lane l: group g=l>>4 handles neighbors j+g; slot s=l&15 covers
// columns 4s..4s+3 (uint2 = 4 bf16). shfl_xor(16,32) butterfly merges groups.
// MODE 0: raw. MODE 1: apply prev-layer BN+ReLU per gathered value.
// ---------------------------------------------------------------------------
template <int MODE>
__global__ __launch_bounds__(256)
void agg_kernel(const float* __restrict__ xin, const __hip_bfloat16* __restrict__ xg,
                const int* __restrict__ cnt, const unsigned short* __restrict__ csr,
                const float* __restrict__ stats_prev, const float* __restrict__ gp,
                const float* __restrict__ bep, float* __restrict__ h) {
    int lr = ((blockIdx.x >> 3) << 2) + (threadIdx.x >> 6);
    if (lr >= PSZ) return;
    int row = (blockIdx.x & 7) * PSZ + lr;
    int lane = threadIdx.x & 63;
    int s4 = (lane & 15) * 4;   // column base for this lane
    int g = lane >> 4;          // neighbor group 0..3

    float4 sc4 = make_float4(1.f, 1.f, 1.f, 1.f);
    float4 off4 = make_float4(0.f, 0.f, 0.f, 0.f);
    if (MODE == 1) {
        const float inv = 1.f / (float)NN;
        float4 sm = *(const float4*)(stats_prev + s4);
        float4 sq = *(const float4*)(stats_prev + 64 + s4);
        float4 gg = *(const float4*)(gp + s4);
        float4 bb = *(const float4*)(bep + s4);
        float mu, var;
        mu = sm.x * inv; var = sq.x * inv - mu * mu;
        sc4.x = gg.x * rsqrtf(var + BN_EPS); off4.x = bb.x - mu * sc4.x;
        mu = sm.y * inv; var = sq.y * inv - mu * mu;
        sc4.y = gg.y * rsqrtf(var + BN_EPS); off4.y = bb.y - mu * sc4.y;
        mu = sm.z * inv; var = sq.z * inv - mu * mu;
        sc4.z = gg.z * rsqrtf(var + BN_EPS); off4.z = bb.z - mu * sc4.z;
        mu = sm.w * inv; var = sq.w * inv - mu * mu;
        sc4.w = gg.w * rsqrtf(var + BN_EPS); off4.w = bb.w - mu * sc4.w;
    }

    int m = min(cnt[row], ROWCAP);
    int ids = (int)csr[((size_t)row << 6) + lane];
    const unsigned short* xgp = (const unsigned short*)xg;

    float4 accA = make_float4(0.f, 0.f, 0.f, 0.f);
    float4 accB = make_float4(0.f, 0.f, 0.f, 0.f);
    if (g == 0) {  // self term added by group 0 only
        float4 sv = *(const float4*)(xin + (size_t)row * HD + s4);
        if (MODE == 1) {
            accA.x = fmaxf(fmaf(sv.x, sc4.x, off4.x), 0.f);
            accA.y = fmaxf(fmaf(sv.y, sc4.y, off4.y), 0.f);
            accA.z = fmaxf(fmaf(sv.z, sc4.z, off4.z), 0.f);
            accA.w = fmaxf(fmaf(sv.w, sc4.w, off4.w), 0.f);
        } else {
            accA = sv;
        }
    }

#define ACC_U2(ACC, U)                                                        \
    {                                                                         \
        float v0 = __uint_as_float((U).x << 16);                              \
        float v1 = __uint_as_float((U).x & 0xffff0000u);                      \
        float v2 = __uint_as_float((U).y << 16);                              \
        float v3 = __uint_as_float((U).y & 0xffff0000u);                      \
        if (MODE == 1) {                                                      \
            ACC.x += fmaxf(fmaf(v0, sc4.x, off4.x), 0.f);                     \
            ACC.y += fmaxf(fmaf(v1, sc4.y, off4.y), 0.f);                     \
            ACC.z += fmaxf(fmaf(v2, sc4.z, off4.z), 0.f);                     \
            ACC.w += fmaxf(fmaf(v3, sc4.w, off4.w), 0.f);                     \
        } else {                                                              \
            ACC.x += v0; ACC.y += v1; ACC.z += v2; ACC.w += v3;               \
        }                                                                     \
    }

    int j = 0;
    for (; j + 8 <= m; j += 8) {  // 8 neighbors per iter: 2 loads/lane
        int nb0 = __shfl(ids, j + g);
        int nb1 = __shfl(ids, j + 4 + g);
        uint2 u0 = *(const uint2*)(xgp + ((size_t)nb0 << 6) + s4);
        uint2 u1 = *(const uint2*)(xgp + ((size_t)nb1 << 6) + s4);
        ACC_U2(accA, u0);
        ACC_U2(accB, u1);
    }
    for (; j < m; j += 4) {  // tail: up to 4 neighbors, predicated by group
        int nb = __shfl(ids, j + g);  // j wave-uniform; shfl unconditional
        if (j + g < m) {
            uint2 u = *(const uint2*)(xgp + ((size_t)nb << 6) + s4);
            ACC_U2(accA, u);
        }
    }
#undef ACC_U2

    float4 acc = make_float4(accA.x + accB.x, accA.y + accB.y,
                             accA.z + accB.z, accA.w + accB.w);
    // butterfly across the 4 groups (lanes xor 16, 32)
    acc.x += __shfl_xor(acc.x, 16);
    acc.y += __shfl_xor(acc.y, 16);
    acc.z += __shfl_xor(acc.z, 16);
    acc.w += __shfl_xor(acc.w, 16);
    acc.x += __shfl_xor(acc.x, 32);
    acc.y += __shfl_xor(acc.y, 32);
    acc.z += __shfl_xor(acc.z, 32);
    acc.w += __shfl_xor(acc.w, 32);

    if (g == 0)
        *(float4*)(h + (size_t)row * HD + s4) = acc;
}

// ---------------------------------------------------------------------------
// Fused MLP + BN-stats epilogue (R16, unchanged). Optional bf16 dual-write.
// ---------------------------------------------------------------------------
__global__ __launch_bounds__(256)
void mlp_kernel(const float* __restrict__ hin, float* __restrict__ hout,
                const float* __restrict__ W1, const float* __restrict__ b1,
                const float* __restrict__ W2, const float* __restrict__ b2,
                float* __restrict__ stats, __hip_bfloat16* __restrict__ xbr) {
    __shared__ float sh[128 * 65];
    __shared__ float sW[64 * 64];
    __shared__ float sb[64];
    __shared__ float red[2][4][64];
    int tid = threadIdx.x;
    int base = blockIdx.x * 128;

    for (int i = tid; i < 4096; i += 256) sW[i] = W1[i];
    if (tid < 64) sb[tid] = b1[tid];
#pragma unroll
    for (int i = 0; i < 8; i++) {
        int i4 = tid + 256 * i;
        int row = i4 >> 4, col = (i4 & 15) * 4;
        int grow = base + row;
        float4 v = (grow < NN) ? *(const float4*)(hin + (size_t)grow * HD + col)
                               : make_float4(0.f, 0.f, 0.f, 0.f);
        float* d = sh + row * 65 + col;
        d[0] = v.x; d[1] = v.y; d[2] = v.z; d[3] = v.w;
    }
    __syncthreads();

    int wv = tid >> 6;
    int lane = tid & 63;

    float acc0[16], acc1[16];
    // ---- GEMM1 ----
#pragma unroll
    for (int j = 0; j < 16; j++) { acc0[j] = sb[wv * 16 + j]; acc1[j] = acc0[j]; }
    for (int k = 0; k < 64; k++) {
        float a0 = sh[lane * 65 + k];
        float a1 = sh[(64 + lane) * 65 + k];
        const float4* wr = (const float4*)(sW + k * 64 + wv * 16);
#pragma unroll
        for (int q = 0; q < 4; q++) {
            float4 w = wr[q];
            acc0[4 * q + 0] = fmaf(a0, w.x, acc0[4 * q + 0]);
            acc0[4 * q + 1] = fmaf(a0, w.y, acc0[4 * q + 1]);
            acc0[4 * q + 2] = fmaf(a0, w.z, acc0[4 * q + 2]);
            acc0[4 * q + 3] = fmaf(a0, w.w, acc0[4 * q + 3]);
            acc1[4 * q + 0] = fmaf(a1, w.x, acc1[4 * q + 0]);
            acc1[4 * q + 1] = fmaf(a1, w.y, acc1[4 * q + 1]);
            acc1[4 * q + 2] = fmaf(a1, w.z, acc1[4 * q + 2]);
            acc1[4 * q + 3] = fmaf(a1, w.w, acc1[4 * q + 3]);
        }
    }
    __syncthreads();

    // t = ReLU(acc) overwrites sh; restage W2/b2
#pragma unroll
    for (int j = 0; j < 16; j++) {
        sh[lane * 65 + wv * 16 + j] = fmaxf(acc0[j], 0.f);
        sh[(64 + lane) * 65 + wv * 16 + j] = fmaxf(acc1[j], 0.f);
    }
    for (int i = tid; i < 4096; i += 256) sW[i] = W2[i];
    if (tid < 64) sb[tid] = b2[tid];
    __syncthreads();

    // ---- GEMM2 ----
#pragma unroll
    for (int j = 0; j < 16; j++) { acc0[j] = sb[wv * 16 + j]; acc1[j] = acc0[j]; }
    for (int k = 0; k < 64; k++) {
        float a0 = sh[lane * 65 + k];
        float a1 = sh[(64 + lane) * 65 + k];
        const float4* wr = (const float4*)(sW + k * 64 + wv * 16);
#pragma unroll
        for (int q = 0; q < 4; q++) {
            float4 w = wr[q];
            acc0[4 * q + 0] = fmaf(a0, w.x, acc0[4 * q + 0]);
            acc0[4 * q + 1] = fmaf(a0, w.y, acc0[4 * q + 1]);
            acc0[4 * q + 2] = fmaf(a0, w.z, acc0[4 * q + 2]);
            acc0[4 * q + 3] = fmaf(a0, w.w, acc0[4 * q + 3]);
            acc1[4 * q + 0] = fmaf(a1, w.x, acc1[4 * q + 0]);
            acc1[4 * q + 1] = fmaf(a1, w.y, acc1[4 * q + 1]);
            acc1[4 * q + 2] = fmaf(a1, w.z, acc1[4 * q + 2]);
            acc1[4 * q + 3] = fmaf(a1, w.w, acc1[4 * q + 3]);
        }
    }
    __syncthreads();
#pragma unroll
    for (int j = 0; j < 16; j++) {
        sh[lane * 65 + wv * 16 + j] = acc0[j];
        sh[(64 + lane) * 65 + wv * 16 + j] = acc1[j];
    }
    __syncthreads();

    // coalesced stores: fp32 always; bf16 raw table if requested
#pragma unroll
    for (int i = 0; i < 8; i++) {
        int i4 = tid + 256 * i;
        int row = i4 >> 4, col = (i4 & 15) * 4;
        int grow = base + row;
        if (grow < NN) {
            const float* s = sh + row * 65 + col;
            float4 v = make_float4(s[0], s[1], s[2], s[3]);
            *(float4*)(hout + (size_t)grow * HD + col) = v;
            if (xbr) {
                union { ushort4 u; __hip_bfloat16 b[4]; } p;
                p.b[0] = __float2bfloat16(v.x);
                p.b[1] = __float2bfloat16(v.y);
                p.b[2] = __float2bfloat16(v.z);
                p.b[3] = __float2bfloat16(v.w);
                *(ushort4*)((unsigned short*)xbr + (size_t)grow * HD + col) = p.u;
            }
        }
    }

    // ---- fused BN-stats partials ----
    {
        int col = tid & 63;
        int r0 = (tid >> 6) * 32;
        float s = 0.f, ss = 0.f;
#pragma unroll
        for (int r = 0; r < 32; r++) {
            float v = (base + r0 + r < NN) ? sh[(r0 + r) * 65 + col] : 0.f;
            s += v;
            ss += v * v;
        }
        red[0][tid >> 6][col] = s;
        red[1][tid >> 6][col] = ss;
        __syncthreads();
        if (tid < 64) {
            float S = red[0][0][col] + red[0][1][col] + red[0][2][col] + red[0][3][col];
            atomicAdd(stats + col, S);
        } else if (tid < 128) {
            float SS = red[1][0][col] + red[1][1][col] + red[1][2][col] + red[1][3][col];
            atomicAdd(stats + 64 + col, SS);
        }
    }
}

// ---------------------------------------------------------------------------
// Final BatchNorm + affine + ReLU with fused mean-pool partials (R16).
// ---------------------------------------------------------------------------
__global__ __launch_bounds__(256)
void norm_kernel(float* h, const float* __restrict__ stats,
                 const float* __restrict__ g, const float* __restrict__ be,
                 const int* __restrict__ batch, float* __restrict__ psums) {
    __shared__ float sg[2][64];
    if (threadIdx.x < 128) sg[threadIdx.x >> 6][threadIdx.x & 63] = 0.f;
    __syncthreads();
    size_t i4 = (size_t)blockIdx.x * 256 + threadIdx.x;
    int row = (int)(i4 >> 4);            // 16 threads (4 cols each) per row
    int base_row = blockIdx.x * 16;
    int g0 = batch[base_row];
    size_t off = i4 * 4;
    int col = (int)(off & 63);
    float4 v = *(const float4*)(h + off);
    float4 sm = *(const float4*)(stats + col);
    float4 sq = *(const float4*)(stats + 64 + col);
    float4 gg = *(const float4*)(g + col);
    float4 bb = *(const float4*)(be + col);
    const float inv = 1.f / (float)NN;
    float4 o;
    {
        float mu = sm.x * inv, var = sq.x * inv - mu * mu;
        float sc = gg.x * rsqrtf(var + BN_EPS);
        o.x = fmaxf((v.x - mu) * sc + bb.x, 0.f);
    }
    {
        float mu = sm.y * inv, var = sq.y * inv - mu * mu;
        float sc = gg.y * rsqrtf(var + BN_EPS);
        o.y = fmaxf((v.y - mu) * sc + bb.y, 0.f);
    }
    {
        float mu = sm.z * inv, var = sq.z * inv - mu * mu;
        float sc = gg.z * rsqrtf(var + BN_EPS);
        o.z = fmaxf((v.z - mu) * sc + bb.z, 0.f);
    }
    {
        float mu = sm.w * inv, var = sq.w * inv - mu * mu;
        float sc = gg.w * rsqrtf(var + BN_EPS);
        o.w = fmaxf((v.w - mu) * sc + bb.w, 0.f);
    }
    *(float4*)(h + off) = o;

    // pool partials
    int dg = batch[row] - g0;
    if (dg <= 1) {
        atomicAdd(&sg[dg][col + 0], o.x);
        atomicAdd(&sg[dg][col + 1], o.y);
        atomicAdd(&sg[dg][col + 2], o.z);
        atomicAdd(&sg[dg][col + 3], o.w);
    } else {  // >2 graphs in one 16-row window (never at ~3125 rows/graph)
        int gid = g0 + dg;
        atomicAdd(&psums[gid * HD + col + 0], o.x);
        atomicAdd(&psums[gid * HD + col + 1], o.y);
        atomicAdd(&psums[gid * HD + col + 2], o.z);
        atomicAdd(&psums[gid * HD + col + 3], o.w);
    }
    __syncthreads();
    if (threadIdx.x < 128) {
        int d = threadIdx.x >> 6;
        int c = threadIdx.x & 63;
        float s = sg[d][c];
        if (g0 + d < NG && s != 0.f) atomicAdd(&psums[(g0 + d) * HD + c], s);
    }
}

// ---------------------------------------------------------------------------
// Pool finalize (R16, unchanged).
// ---------------------------------------------------------------------------
__device__ __forceinline__ int lower_bound_batch(const int* __restrict__ b, int val) {
    int lo = 0, hi = NN;
    while (lo < hi) {
        int mid = (lo + hi) >> 1;
        if (b[mid] < val) lo = mid + 1;
        else hi = mid;
    }
    return lo;
}

__global__ __launch_bounds__(1024)
void pool_finalize_kernel(const float* __restrict__ sums, const int* __restrict__ batch,
                          float* __restrict__ out) {
    int g = threadIdx.x >> 6;
    int col = threadIdx.x & 63;
    int s = lower_bound_batch(batch, g);
    int e = lower_bound_batch(batch, g + 1);
    float cnt = (float)(e - s);
    out[g * HD + col] = sums[g * HD + col] / fmaxf(cnt, 1.f);
}

extern "C" void kernel_launch(void* const* d_in, const int* in_sizes, int n_in,
                              void* d_out, int out_size, void* d_ws, size_t ws_size,
                              hipStream_t stream) {
    const float* x = (const float*)d_in[0];
    const int* ei = (const int*)d_in[1];
    const int* batch = (const int*)d_in[2];
    const float* W1_0 = (const float*)d_in[3];
    const float* b1_0 = (const float*)d_in[4];
    const float* W2_0 = (const float*)d_in[5];
    const float* b2_0 = (const float*)d_in[6];
    const float* g_0 = (const float*)d_in[7];
    const float* be_0 = (const float*)d_in[8];
    const float* W1_1 = (const float*)d_in[9];
    const float* b1_1 = (const float*)d_in[10];
    const float* W2_1 = (const float*)d_in[11];
    const float* b2_1 = (const float*)d_in[12];
    const float* g_1 = (const float*)d_in[13];
    const float* be_1 = (const float*)d_in[14];

    float* out = (float*)d_out;  // raw L0 h2 -> raw L1 h2 -> final normalized

    // workspace layout (~26 MB)
    float* buf_h = (float*)d_ws;                       // NN*HD f32 (12.8 MB)
    float* stats0 = buf_h + (size_t)NN * HD;           // 128 f32
    float* stats1 = stats0 + 128;                      // 128 f32
    float* psums = stats1 + 128;                       // 1024 f32
    int* cnt = (int*)(psums + 1024);                   // NN int
    unsigned short* csr = (unsigned short*)(cnt + NN); // NN*ROWCAP u16 (6.4 MB)
    __hip_bfloat16* xb = (__hip_bfloat16*)(csr + (size_t)NN * ROWCAP);  // NN*HD bf16

    dim3 b256(256);
    int mlp_grid = (NN + 127) / 128;              // 391
    int norm_grid = (NN * HD / 4 + 255) / 256;    // 3125
    int sct_grid = ((NE + 1023) / 1024) * NPART;  // 782 chunks x 8 = 6256
    int agg_grid = NPART * PBLK;                  // 8 x 1563 = 12504

    // ---- padded-CSR build (2 dispatches) ----
    prep_kernel<<<norm_grid, b256, 0, stream>>>(x, xb, cnt, stats0, stats1, psums);
    scatter_kernel<<<sct_grid, b256, 0, stream>>>(ei, cnt, csr);

    // ---- layer 0 ----
    agg_kernel<0><<<agg_grid, b256, 0, stream>>>(x, xb, cnt, csr,
                                                 nullptr, nullptr, nullptr, buf_h);
    // mlp writes raw-L0 bf16 back into xb: safe under dispatch boundaries
    // (agg has fully consumed xb before mlp starts).
    mlp_kernel<<<mlp_grid, b256, 0, stream>>>(buf_h, out, W1_0, b1_0, W2_0, b2_0,
                                              stats0, xb);

    // ---- layer 1 (agg applies layer-0 BN+ReLU on the fly) ----
    agg_kernel<1><<<agg_grid, b256, 0, stream>>>(out, xb, cnt, csr,
                                                 stats0, g_0, be_0, buf_h);
    mlp_kernel<<<mlp_grid, b256, 0, stream>>>(buf_h, out, W1_1, b1_1, W2_1, b2_1,
                                              stats1, (__hip_bfloat16*)nullptr);

    // ---- final norm + fused pool partials, then tiny finalize ----
    norm_kernel<<<norm_grid, b256, 0, stream>>>(out, stats1, g_1, be_1, batch, psums);
    pool_finalize_kernel<<<1, dim3(1024), 0, stream>>>(psums, batch, out + (size_t)NN * HD);
}